// Round 9
// baseline (181.873 us; speedup 1.0000x reference)
//
#include <hip/hip_runtime.h>
#include <hip/hip_bf16.h>
#include <cstdint>
#include <cstddef>

// Problem dims (fixed by the reference).
#define M_DIM 8192
#define K_DIM 2048
#define N_DIM 2048

// 256x256 tile, BK=64, 8 waves. Loose pipelined schedule (R9):
// 2 raw barriers + 1 counted vmcnt per K-tile; NO per-cluster lgkm drains —
// compiler emits fine-grained lgkmcnt(N) per use, so ds_reads drain DURING
// MFMA clusters instead of before them.
#define BM 256
#define BN 256
#define BK 64
#define NT (K_DIM / BK)  // 32 K-tiles

typedef __bf16 bf16x8 __attribute__((ext_vector_type(8)));
typedef float f32x4 __attribute__((ext_vector_type(4)));
typedef unsigned short ushort8_t __attribute__((ext_vector_type(8)));

__device__ __forceinline__ unsigned short f32_to_bf16_rne(float f) {
  unsigned int u = __builtin_bit_cast(unsigned int, f);
  u += 0x7fffu + ((u >> 16) & 1u);
  return (unsigned short)(u >> 16);
}

// ---------------------------------------------------------------------------
// Fused conversion kernel (single launch):
//   blocks [0, 1024):   w (f32 [K,N]) -> wt (bf16 [N,K]) transpose, 64x64 tiles
//   blocks [1024, 3072): x (f32 [M,K]) -> xb (bf16 [M,K]), 8 elems/thread
// ---------------------------------------------------------------------------
__global__ void cvt_fused_kernel(const float* __restrict__ x,
                                 unsigned short* __restrict__ xb,
                                 const float* __restrict__ w,
                                 unsigned short* __restrict__ wt) {
  __shared__ float tile[64][65];
  if (blockIdx.x < 1024) {
    const int tx = threadIdx.x & 63;
    const int ty = threadIdx.x >> 6;  // 0..3
    const int n0 = (blockIdx.x & 31) * 64;
    const int k0 = (blockIdx.x >> 5) * 64;
#pragma unroll
    for (int r = 0; r < 16; ++r) {
      const int row = r * 4 + ty;  // k-local
      tile[row][tx] = w[(size_t)(k0 + row) * N_DIM + n0 + tx];
    }
    __syncthreads();
#pragma unroll
    for (int r = 0; r < 16; ++r) {
      const int row = r * 4 + ty;  // n-local
      wt[(size_t)(n0 + row) * K_DIM + k0 + tx] = f32_to_bf16_rne(tile[tx][row]);
    }
  } else {
    const size_t n = (size_t)M_DIM * K_DIM;
    size_t i = ((size_t)(blockIdx.x - 1024) * blockDim.x + threadIdx.x) * 8;
    const size_t stride = (size_t)2048 * blockDim.x * 8;
    for (; i < n; i += stride) {
      const float4 f0 = *reinterpret_cast<const float4*>(x + i);
      const float4 f1 = *reinterpret_cast<const float4*>(x + i + 4);
      ushort8_t o;
      o[0] = f32_to_bf16_rne(f0.x);
      o[1] = f32_to_bf16_rne(f0.y);
      o[2] = f32_to_bf16_rne(f0.z);
      o[3] = f32_to_bf16_rne(f0.w);
      o[4] = f32_to_bf16_rne(f1.x);
      o[5] = f32_to_bf16_rne(f1.y);
      o[6] = f32_to_bf16_rne(f1.z);
      o[7] = f32_to_bf16_rne(f1.w);
      *reinterpret_cast<ushort8_t*>(xb + i) = o;
    }
  }
}

// ---------------------------------------------------------------------------
// GEMM: 256x256 bf16, loose pipelined schedule. C = A[M,K] * Bt[N,K]^T.
// Per K-tile t (buf = t&1), program order:
//   rd b1(t)                      // shadow: Q00
//   Q00(b0,aL)  Q01(b1,aL)        // fine-grained auto-waits
//   rd aH(t) into a[]             // reuse: Q01's MFMAs already issued
//   Q10(b0,aH)                    // lazy per-frag waits on aH
//   lgkm0 (free); BARR            // WAR gate: buf(t) fully read by all waves
//   STAGE tile t+2 -> buf(t)      // 8 gl_lds
//   VMCNT(8); BARR                // publish tile t+1 (t+2's 8 stay in flight)
//   rd b0(t+1)                    // shadow: Q11
//   Q11(b1,aH)
//   rd aL(t+1)                    // exposed ~first-use wait only
// ---------------------------------------------------------------------------
__device__ __forceinline__ void async_copy16(unsigned short* lds_dst,
                                             const unsigned short* g_src) {
  __builtin_amdgcn_global_load_lds(
      (__attribute__((address_space(1))) void*)g_src,
      (__attribute__((address_space(3))) void*)lds_dst,
      16, 0, 0);
}

#define BARR() __builtin_amdgcn_s_barrier()
#define LGKM0()                                       \
  asm volatile("s_waitcnt lgkmcnt(0)" ::: "memory");  \
  __builtin_amdgcn_sched_barrier(0)
#define PRIO(p) __builtin_amdgcn_s_setprio(p)
#define VMCNT(n) asm volatile("s_waitcnt vmcnt(" #n ")" ::: "memory")

// Stage one half-tile (128 rows x 64 k) of A (isB=0) or B (isB=1), half h,
// K-tile t, into buf (t&1). 2 x global_load_lds(16B) per thread.
#define STG(isB, h, t)                                                       \
  do {                                                                       \
    const unsigned short* _src =                                             \
        ((isB) ? Bt : A) +                                                   \
        (size_t)(((isB) ? n0 : m0) + (h) * 128 + row0) * K_DIM + (t) * 64 +  \
        sg8;                                                                 \
    unsigned short* _dst = &smem[((t) & 1) * 32768 + (isB) * 16384 +         \
                                 (h) * 8192 + dst0];                         \
    async_copy16(_dst, _src);                                                \
    async_copy16(_dst + 4096, _src + 64 * K_DIM);                            \
  } while (0)

#define STG_TILE(t)                                                          \
  do { STG(0, 0, t); STG(0, 1, t); STG(1, 0, t); STG(1, 1, t); } while (0)

// ds_read the wave's A fragments for M-half moff (4 frags x 2 kslices).
#define RD_A(buf, moff)                                                      \
  do {                                                                       \
    _Pragma("unroll") for (int mf = 0; mf < 4; ++mf) {                       \
      const int _r = ((buf) * 32768) + (wm * 128 + ((moff) + mf) * 16 + lr) * 64; \
      a[mf][0] = *reinterpret_cast<const bf16x8*>(&smem[_r + sl0]);          \
      a[mf][1] = *reinterpret_cast<const bf16x8*>(&smem[_r + sl1]);          \
    }                                                                        \
  } while (0)

// ds_read the wave's B fragments for N-half noff into bdst (2 frags x 2 ks).
#define RD_B(bdst, buf, noff)                                                \
  do {                                                                       \
    _Pragma("unroll") for (int nf = 0; nf < 2; ++nf) {                       \
      const int _r = ((buf) * 32768) + 16384 +                               \
                     (wn * 64 + ((noff) + nf) * 16 + lr) * 64;               \
      bdst[nf][0] = *reinterpret_cast<const bf16x8*>(&smem[_r + sl0]);       \
      bdst[nf][1] = *reinterpret_cast<const bf16x8*>(&smem[_r + sl1]);       \
    }                                                                        \
  } while (0)

// 16 MFMA: one C-quadrant (4 m-frags x 2 n-frags x 2 kslices).
#define MM(bsel, moff, noff)                                                 \
  do {                                                                       \
    _Pragma("unroll") for (int mf = 0; mf < 4; ++mf) {                       \
      _Pragma("unroll") for (int nf = 0; nf < 2; ++nf) {                     \
        _Pragma("unroll") for (int ks = 0; ks < 2; ++ks) {                   \
          acc[(moff) + mf][(noff) + nf] =                                    \
              __builtin_amdgcn_mfma_f32_16x16x32_bf16(                       \
                  a[mf][ks], bsel[nf][ks], acc[(moff) + mf][(noff) + nf],    \
                  0, 0, 0);                                                  \
        }                                                                    \
      }                                                                      \
    }                                                                        \
  } while (0)

__global__ __launch_bounds__(512, 2) void gemm_kernel(
    const unsigned short* __restrict__ A,   // bf16 [M,K]
    const unsigned short* __restrict__ Bt,  // bf16 [N,K]
    float* __restrict__ C) {                // f32 [M,N]
  __shared__ unsigned short smem[2 * 32768];  // 128 KiB: [buf][A|B][256][64]

  const int tid = threadIdx.x;
  const int lane = tid & 63;
  const int wv = tid >> 6;          // 0..7
  const int wm = wv >> 2;           // 0..1
  const int wn = wv & 3;            // 0..3
  const int lr = lane & 15;
  const int kg = lane >> 4;         // 0..3
  // Swizzled ds_read slot offsets (elements): slot = (ks*4+kg) ^ (row&7),
  // and row&7 == lr&7 for all fragment rows.
  const int sl0 = ((kg ^ (lr & 7)) * 8);
  const int sl1 = (((kg + 4) ^ (lr & 7)) * 8);

  // XCD-aware chunked swizzle (nwg=256, divisible by 8).
  const int bid = blockIdx.x;
  const int wgid = (bid & 7) * 32 + (bid >> 3);
  const int bm = wgid >> 3;  // 0..31
  const int bn = wgid & 7;   // 0..7
  const int m0 = bm * BM;
  const int n0 = bn * BN;

  // Staging constants: thread covers chunks c = l*512 + tid (l=0,1);
  // row = c>>3, lds slot = c&7, global slot = (c&7) ^ (row&7).
  const int row0 = tid >> 3;                                  // 0..63
  const int sg8 = (((tid & 7) ^ ((tid >> 3) & 7)) * 8);       // global k-offset
  const int dst0 = wv * 512;  // wave-uniform LDS elem offset within region

  f32x4 acc[8][4] = {};
  bf16x8 a[4][2], b0[2][2], b1[2][2];

  // Prologue: stage tiles 0 and 1 fully; publish tile0 (tile1's 8 in flight);
  // issue aL,b0 of tile0.
  STG_TILE(0);
  STG_TILE(1);
  VMCNT(8);
  BARR();
  RD_A(0, 0);
  RD_B(b0, 0, 0);

#pragma unroll 1
  for (int j = 0; j < 15; ++j) {
    const int e2 = 2 * j + 2;
    const int o2 = 2 * j + 3;

    // ======== tile e = 2j (buf0) ========
    RD_B(b1, 0, 2);                      // shadow: Q00
    PRIO(1); MM(b0, 0, 0); PRIO(0);      // Q00 (waits aL,b0 fine-grained)
    PRIO(1); MM(b1, 0, 2); PRIO(0);      // Q01 (waits b1)
    RD_A(0, 4);                          // aH(e); lazy waits inside Q10
    PRIO(1); MM(b0, 4, 0); PRIO(0);      // Q10
    LGKM0();                             // ~free: Q10's last wait covered aH
    BARR();                              // WAR: buf0 fully read by all waves
    STG_TILE(e2);                        // restage buf0 with tile e+2
    VMCNT(8);                            // drain tile o's 8 (e+2's 8 remain)
    BARR();                              // publish tile o (buf1)
    RD_B(b0, 1, 0);                      // b0(o); shadow: Q11
    PRIO(1); MM(b1, 4, 2); PRIO(0);      // Q11
    RD_A(1, 0);                          // aL(o); exposed ~first-use only

    // ======== tile o = 2j+1 (buf1) ========
    RD_B(b1, 1, 2);
    PRIO(1); MM(b0, 0, 0); PRIO(0);
    PRIO(1); MM(b1, 0, 2); PRIO(0);
    RD_A(1, 4);
    PRIO(1); MM(b0, 4, 0); PRIO(0);
    LGKM0();
    BARR();
    STG_TILE(o2);
    VMCNT(8);                            // drain tile e+2's 8
    BARR();                              // publish tile e+2 (buf0)
    RD_B(b0, 0, 0);
    PRIO(1); MM(b1, 4, 2); PRIO(0);
    RD_A(0, 0);
  }

  // ======== tile 30 (buf0): no restage; publish tile 31 ========
  RD_B(b1, 0, 2);
  PRIO(1); MM(b0, 0, 0); PRIO(0);
  PRIO(1); MM(b1, 0, 2); PRIO(0);
  RD_A(0, 4);
  PRIO(1); MM(b0, 4, 0); PRIO(0);
  LGKM0();
  BARR();
  VMCNT(0);                              // only tile 31's 8 outstanding
  BARR();                                // publish tile 31 (buf1)
  RD_B(b0, 1, 0);
  PRIO(1); MM(b1, 4, 2); PRIO(0);
  RD_A(1, 0);

  // ======== tile 31 (buf1): final ========
  RD_B(b1, 1, 2);
  PRIO(1); MM(b0, 0, 0); PRIO(0);
  PRIO(1); MM(b1, 0, 2); PRIO(0);
  RD_A(1, 4);
  PRIO(1); MM(b0, 4, 0); PRIO(0);
  PRIO(1); MM(b1, 4, 2); PRIO(0);

  // Epilogue: C/D layout col = lane&15, row = kg*4 + reg. Plain stores
  // (nontemporal regressed: partial-line HBM writes, WRITE 64->84 MB).
  const int crow0 = m0 + wm * 128 + kg * 4;
  const int ccol0 = n0 + wn * 64 + lr;
#pragma unroll
  for (int mi = 0; mi < 8; ++mi) {
#pragma unroll
    for (int ni = 0; ni < 4; ++ni) {
#pragma unroll
      for (int r = 0; r < 4; ++r) {
        C[(size_t)(crow0 + mi * 16 + r) * N_DIM + ccol0 + ni * 16] =
            acc[mi][ni][r];
      }
    }
  }
}

// ---------------------------------------------------------------------------
extern "C" void kernel_launch(void* const* d_in, const int* in_sizes, int n_in,
                              void* d_out, int out_size, void* d_ws,
                              size_t ws_size, hipStream_t stream) {
  const float* x = (const float*)d_in[0];  // [M,K] f32
  const float* w = (const float*)d_in[1];  // [K,N] f32
  float* out = (float*)d_out;              // [M,N] f32

  unsigned short* xb = (unsigned short*)d_ws;                         // 32 MiB
  unsigned short* wt = (unsigned short*)((char*)d_ws +
                                         (size_t)M_DIM * K_DIM * 2);  // 8 MiB

  cvt_fused_kernel<<<3072, 256, 0, stream>>>(x, xb, w, wt);

  const int grid = (M_DIM / BM) * (N_DIM / BN);  // 32 * 8 = 256
  gemm_kernel<<<grid, 512, 0, stream>>>(xb, wt, out);
}

// Round 10
// 170.852 us; speedup vs baseline: 1.0645x; 1.0645x over previous
//
#include <hip/hip_runtime.h>
#include <hip/hip_bf16.h>
#include <cstdint>
#include <cstddef>

// Problem dims (fixed by the reference).
#define M_DIM 8192
#define K_DIM 2048
#define N_DIM 2048

// i8 GEMM config: 128x256 tile, BK=64, 4 waves (2Mx2N), wave-tile 64x128.
// mfma_i32_32x32x32_i8: A/B 4 VGPR (16 i8/lane), C/D 16 i32.
// Fragment-major operand layout (pre-packed by prep kernels):
//   A_fm[m_frag(256)][k_tile(64)][lane(64)][16B], frag elem: row=l&31,
//   k = kt*32 + (l>>5)*16 + j.  Same for B (wt_fm, col=l&31).
// All gl_lds and ds_reads are lane-linear -> zero bank conflicts, no swizzle.

typedef int i32x4 __attribute__((ext_vector_type(4)));
typedef int i32x16 __attribute__((ext_vector_type(16)));

// ws layout (bytes)
#define AFM_OFF   0u
#define WFM_OFF   16777216u   // 16 MiB
#define SCL_OFF   20971520u   // +4 MiB
#define SCLI_OFF  21004288u   // +32 KiB

__device__ __forceinline__ int clamp_rne(float v, float si) {
  int q = (int)rintf(v * si);
  q = q > 127 ? 127 : (q < -127 ? -127 : q);
  return q & 255;
}

__device__ __forceinline__ int pack4(float a, float b, float c, float d,
                                     float si) {
  return clamp_rne(a, si) | (clamp_rne(b, si) << 8) |
         (clamp_rne(c, si) << 16) | (clamp_rne(d, si) << 24);
}

// ---------------------------------------------------------------------------
// prep1: blocks [0,256): per-row absmax of x -> scales, scales_inv.
//        blocks [256,768): w (f32 [K,N]) -> wt_fm (i8 fragment-major).
// ---------------------------------------------------------------------------
__global__ void prep1_kernel(const float* __restrict__ x,
                             float* __restrict__ scales,
                             float* __restrict__ scales_inv,
                             const float* __restrict__ w,
                             signed char* __restrict__ wt_fm) {
  __shared__ float wlds[32][256];  // 32 KiB; bank = col%32 -> conflict-free
  const int tid = threadIdx.x;
  if (blockIdx.x < 256) {
    // 32 rows/block, 8 threads/row, 256 f32/thread.
    const int rloc = tid >> 3;
    const int part = tid & 7;
    const int row = blockIdx.x * 32 + rloc;
    const float4* xr =
        (const float4*)(x + (size_t)row * K_DIM + part * 256);
    float m = 0.f;
#pragma unroll 16
    for (int i = 0; i < 64; ++i) {
      const float4 v = xr[i];
      m = fmaxf(m, fmaxf(fmaxf(fabsf(v.x), fabsf(v.y)),
                         fmaxf(fabsf(v.z), fabsf(v.w))));
    }
#pragma unroll
    for (int off = 1; off < 8; off <<= 1) m = fmaxf(m, __shfl_xor(m, off, 8));
    if (part == 0) {
      scales[row] = m * (1.f / 127.f);
      scales_inv[row] = 127.f / fmaxf(m, 1e-20f);
    }
  } else {
    // w-pack: block b covers k-tile kb (32 k-rows) x 256 n-cols.
    const int b = blockIdx.x - 256;  // 0..511
    const int bn = b & 7;            // n-col block (256 each)
    const int kb = b >> 3;           // k-tile 0..63
    // load w[kb*32 .. +31][bn*256 .. +255] coalesced
    for (int r = 0; r < 32; ++r)
      wlds[r][tid] = w[(size_t)(kb * 32 + r) * N_DIM + bn * 256 + tid];
    __syncthreads();
    const int l = tid & 63;
    const int h16 = (l >> 5) * 16;
    const int col = (l & 31);
#pragma unroll
    for (int g = 0; g < 2; ++g) {
      const int nfl = g * 4 + (tid >> 6);  // 0..7
      const float* src = &wlds[0][0] + nfl * 32 + col;
      i32x4 out;
#pragma unroll
      for (int q = 0; q < 4; ++q) {
        out[q] = pack4(src[(h16 + q * 4 + 0) * 256], src[(h16 + q * 4 + 1) * 256],
                       src[(h16 + q * 4 + 2) * 256], src[(h16 + q * 4 + 3) * 256],
                       1.f);
      }
      *(i32x4*)(wt_fm + (size_t)(bn * 8 + nfl) * 65536 + (size_t)kb * 1024 +
                l * 16) = out;
    }
  }
}

// ---------------------------------------------------------------------------
// prep2: x (f32) -> A_fm (i8 fragment-major), using scales_inv.
// One thread -> one 16B fragment chunk (reads 64B of one row, L3-warm).
// ---------------------------------------------------------------------------
__global__ void prep2_kernel(const float* __restrict__ x,
                             const float* __restrict__ scales_inv,
                             signed char* __restrict__ a_fm) {
  const int o = blockIdx.x * 256 + threadIdx.x;  // 0 .. 1M-1
  const int l = o & 63;
  const int kt = (o >> 6) & 63;
  const int mf = o >> 12;
  const int row = mf * 32 + (l & 31);
  const int k0 = kt * 32 + (l >> 5) * 16;
  const float si = scales_inv[row];
  const float4* src = (const float4*)(x + (size_t)row * K_DIM + k0);
  const float4 v0 = src[0], v1 = src[1], v2 = src[2], v3 = src[3];
  i32x4 out;
  out[0] = pack4(v0.x, v0.y, v0.z, v0.w, si);
  out[1] = pack4(v1.x, v1.y, v1.z, v1.w, si);
  out[2] = pack4(v2.x, v2.y, v2.z, v2.w, si);
  out[3] = pack4(v3.x, v3.y, v3.z, v3.w, si);
  *(i32x4*)(a_fm + (size_t)o * 16) = out;
}

// ---------------------------------------------------------------------------
// GEMM i8: C[M,N] f32 = (A_q i8) x (W_q i8)^T * scale_row.
// 512 blocks (2/CU), 256 threads (4 waves 2x2), LDS 48 KiB dbuf.
// ---------------------------------------------------------------------------
__device__ __forceinline__ void async_copy16(signed char* lds_dst,
                                             const signed char* g_src) {
  __builtin_amdgcn_global_load_lds(
      (__attribute__((address_space(1))) void*)g_src,
      (__attribute__((address_space(3))) void*)lds_dst,
      16, 0, 0);
}

#define BARR() __builtin_amdgcn_s_barrier()
#define LGKM0()                                       \
  asm volatile("s_waitcnt lgkmcnt(0)" ::: "memory");  \
  __builtin_amdgcn_sched_barrier(0)
#define PRIO(p) __builtin_amdgcn_s_setprio(p)
#define VMCNT(n) asm volatile("s_waitcnt vmcnt(" #n ")" ::: "memory")

// Stage K-tile t (A 8 KiB + B 16 KiB) into buf t&1: 6 x gl_lds(16B)/thread.
#define STG6(t)                                                              \
  do {                                                                       \
    signed char* _bA = smem + ((t) & 1) * 24576;                             \
    signed char* _bB = _bA + 8192;                                           \
    const size_t _k0 = (size_t)(2 * (t)) * 1024;                             \
    async_copy16(_bA + wv * 1024 + l16,                                      \
                 Afm + (size_t)(bm4 + wv) * 65536 + _k0 + l16);              \
    async_copy16(_bA + 4096 + wv * 1024 + l16,                               \
                 Afm + (size_t)(bm4 + wv) * 65536 + _k0 + 1024 + l16);       \
    async_copy16(_bB + wv * 1024 + l16,                                      \
                 Bfm + (size_t)(bn8 + wv) * 65536 + _k0 + l16);              \
    async_copy16(_bB + 4096 + wv * 1024 + l16,                               \
                 Bfm + (size_t)(bn8 + 4 + wv) * 65536 + _k0 + l16);          \
    async_copy16(_bB + 8192 + wv * 1024 + l16,                               \
                 Bfm + (size_t)(bn8 + wv) * 65536 + _k0 + 1024 + l16);       \
    async_copy16(_bB + 12288 + wv * 1024 + l16,                              \
                 Bfm + (size_t)(bn8 + 4 + wv) * 65536 + _k0 + 1024 + l16);   \
  } while (0)

// Read the wave's 12 fragments (lane-linear, conflict-free).
#define RDT(buf)                                                             \
  do {                                                                       \
    const signed char* _bA = smem + (buf) * 24576;                           \
    const signed char* _bB = _bA + 8192;                                     \
    _Pragma("unroll") for (int nfi = 0; nfi < 4; ++nfi)                      \
      _Pragma("unroll") for (int kt = 0; kt < 2; ++kt)                       \
        bfr[nfi][kt] = *(const i32x4*)(_bB + kt * 8192 +                     \
                                       (wn4 + nfi) * 1024 + l16);            \
    _Pragma("unroll") for (int mfi = 0; mfi < 2; ++mfi)                      \
      _Pragma("unroll") for (int kt = 0; kt < 2; ++kt)                       \
        afr[mfi][kt] = *(const i32x4*)(_bA + kt * 4096 +                     \
                                       (wm2 + mfi) * 1024 + l16);            \
  } while (0)

#define MMT()                                                                \
  do {                                                                       \
    _Pragma("unroll") for (int mfi = 0; mfi < 2; ++mfi)                      \
      _Pragma("unroll") for (int nfi = 0; nfi < 4; ++nfi)                    \
        _Pragma("unroll") for (int kt = 0; kt < 2; ++kt)                     \
          acc[mfi][nfi] = __builtin_amdgcn_mfma_i32_32x32x32_i8(             \
              afr[mfi][kt], bfr[nfi][kt], acc[mfi][nfi], 0, 0, 0);           \
  } while (0)

__global__ __launch_bounds__(256, 2) void gemm_kernel(
    const signed char* __restrict__ Afm,  // i8 fragment-major [256][64][1024B]
    const signed char* __restrict__ Bfm,  // i8 fragment-major [64][64][1024B]
    const float* __restrict__ scales,     // [M] rowabsmax/127
    float* __restrict__ C) {              // f32 [M,N]
  __shared__ signed char smem[2 * 24576];  // 48 KiB
  __shared__ float scale_lds[128];

  const int tid = threadIdx.x;
  const int l = tid & 63;
  const int l16 = l * 16;
  const int wv = tid >> 6;   // 0..3
  const int wm2 = (wv >> 1) * 2;  // A frag base (mf units)
  const int wn4 = (wv & 1) * 4;   // B frag base (nf units)

  // XCD-aware swizzle: nwg=512, 64 per XCD.
  const int bid = blockIdx.x;
  const int wgid = (bid & 7) * 64 + (bid >> 3);
  const int bm = wgid >> 3;   // 0..63
  const int bn = wgid & 7;    // 0..7
  const int bm4 = bm * 4;     // A m_frag base
  const int bn8 = bn * 8;     // B n_frag base
  const int m0 = bm * 128;
  const int n0 = bn * 256;

  if (tid < 128) scale_lds[tid] = scales[m0 + tid];

  i32x16 acc[2][4] = {};
  i32x4 afr[2][2], bfr[4][2];

  STG6(0);
  STG6(1);
  VMCNT(6);  // tile0 arrived (tile1's 6 in flight)
  BARR();

#pragma unroll 1
  for (int j = 0; j < 15; ++j) {
    const int e = 2 * j;
    // tile e (buf0)
    RDT(0);
    LGKM0();
    PRIO(1); MMT(); PRIO(0);
    BARR();           // WAR: buf0 consumed
    STG6(e + 2);
    VMCNT(6);         // drain tile e+1's loads (e+2's 6 remain)
    BARR();           // publish tile e+1
    // tile e+1 (buf1)
    RDT(1);
    LGKM0();
    PRIO(1); MMT(); PRIO(0);
    BARR();           // WAR: buf1 consumed
    STG6(e + 3);
    VMCNT(6);         // drain tile e+2's loads
    BARR();           // publish tile e+2
  }
  // tile 30 (buf0): no restage; publish tile 31.
  RDT(0);
  LGKM0();
  PRIO(1); MMT(); PRIO(0);
  BARR();
  VMCNT(0);
  BARR();
  // tile 31 (buf1): final.
  RDT(1);
  LGKM0();
  PRIO(1); MMT(); PRIO(0);

  // Epilogue: C/D 32x32 layout col=lane&31, row=(reg&3)+8*(reg>>2)+4*(lane>>5).
  const int colb = n0 + (wv & 1) * 128 + (l & 31);
  const int rowb = (wv >> 1) * 64 + 4 * (l >> 5);
#pragma unroll
  for (int mfi = 0; mfi < 2; ++mfi) {
#pragma unroll
    for (int nfi = 0; nfi < 4; ++nfi) {
      const int col = colb + nfi * 32;
#pragma unroll
      for (int r = 0; r < 16; ++r) {
        const int lrow = rowb + mfi * 32 + (r & 3) + 8 * (r >> 2);
        C[(size_t)(m0 + lrow) * N_DIM + col] =
            (float)acc[mfi][nfi][r] * scale_lds[lrow];
      }
    }
  }
}

// ---------------------------------------------------------------------------
extern "C" void kernel_launch(void* const* d_in, const int* in_sizes, int n_in,
                              void* d_out, int out_size, void* d_ws,
                              size_t ws_size, hipStream_t stream) {
  const float* x = (const float*)d_in[0];  // [M,K] f32
  const float* w = (const float*)d_in[1];  // [K,N] f32
  float* out = (float*)d_out;              // [M,N] f32

  signed char* a_fm = (signed char*)d_ws + AFM_OFF;
  signed char* wt_fm = (signed char*)d_ws + WFM_OFF;
  float* scales = (float*)((char*)d_ws + SCL_OFF);
  float* scales_inv = (float*)((char*)d_ws + SCLI_OFF);

  prep1_kernel<<<768, 256, 0, stream>>>(x, scales, scales_inv, w, wt_fm);
  prep2_kernel<<<4096, 256, 0, stream>>>(x, scales_inv, a_fm);
  gemm_kernel<<<512, 256, 0, stream>>>(a_fm, wt_fm, scales, out);
}

// Round 11
// 165.991 us; speedup vs baseline: 1.0957x; 1.0293x over previous
//
#include <hip/hip_runtime.h>
#include <hip/hip_bf16.h>
#include <cstdint>
#include <cstddef>

// Problem dims (fixed by the reference).
#define M_DIM 8192
#define K_DIM 2048
#define N_DIM 2048

// i8 GEMM config: 128x256 tile, BK=64, 4 waves (2Mx2N), wave-tile 64x128.
// mfma_i32_32x32x32_i8: A/B 4 VGPR (16 i8/lane), C/D 16 i32.
// Fragment-major operand layout (pre-packed by prep kernels):
//   A_fm[m_frag(256)][k_tile(64)][lane(64)][16B], frag elem: row=l&31,
//   k = kt*32 + (l>>5)*16 + j.  Same for B (wt_fm, col=l&31).
// All gl_lds and ds_reads are lane-linear -> zero bank conflicts, no swizzle.

typedef int i32x4 __attribute__((ext_vector_type(4)));
typedef int i32x16 __attribute__((ext_vector_type(16)));

// ws layout (bytes)
#define AFM_OFF   0u
#define WFM_OFF   16777216u   // 16 MiB
#define SCL_OFF   20971520u   // +4 MiB
#define SCLI_OFF  21004288u   // +32 KiB

__device__ __forceinline__ int clamp_rne(float v, float si) {
  int q = (int)rintf(v * si);
  q = q > 127 ? 127 : (q < -127 ? -127 : q);
  return q & 255;
}

__device__ __forceinline__ int pack4(float a, float b, float c, float d,
                                     float si) {
  return clamp_rne(a, si) | (clamp_rne(b, si) << 8) |
         (clamp_rne(c, si) << 16) | (clamp_rne(d, si) << 24);
}

// ---------------------------------------------------------------------------
// prep1: blocks [0,2048): per-row absmax, ONE WAVE PER ROW (coalesced 1 KB
//        wave-loads, shfl_xor tree).  Side effect: x becomes L3-resident.
//        blocks [2048,2560): w (f32 [K,N]) -> wt_fm (i8 frag-major), LDS tile.
// ---------------------------------------------------------------------------
__global__ void prep1_kernel(const float* __restrict__ x,
                             float* __restrict__ scales,
                             float* __restrict__ scales_inv,
                             const float* __restrict__ w,
                             signed char* __restrict__ wt_fm) {
  __shared__ float wlds[32][256];  // 32 KiB (w-pack branch only)
  const int tid = threadIdx.x;
  if (blockIdx.x < 2048) {
    const int l = tid & 63;
    const int row = blockIdx.x * 4 + (tid >> 6);  // wave -> row
    const float4* xr = (const float4*)(x + (size_t)row * K_DIM);
    float m = 0.f;
#pragma unroll
    for (int i = 0; i < 8; ++i) {
      const float4 v = xr[i * 64 + l];  // 64 lanes x 16B consecutive
      m = fmaxf(m, fmaxf(fmaxf(fabsf(v.x), fabsf(v.y)),
                         fmaxf(fabsf(v.z), fabsf(v.w))));
    }
#pragma unroll
    for (int off = 32; off >= 1; off >>= 1) m = fmaxf(m, __shfl_xor(m, off));
    if (l == 0) {
      scales[row] = m * (1.f / 127.f);
      scales_inv[row] = 127.f / fmaxf(m, 1e-20f);
    }
  } else {
    // w-pack: block covers k-tile kb (32 k-rows) x 256 n-cols. Coalesced both
    // global sides; LDS reads conflict-free (lane-consecutive addresses).
    const int b = blockIdx.x - 2048;  // 0..511
    const int bn = b & 7;             // n-col block (256 each)
    const int kb = b >> 3;            // k-tile 0..63
    for (int r = 0; r < 32; ++r)
      wlds[r][tid] = w[(size_t)(kb * 32 + r) * N_DIM + bn * 256 + tid];
    __syncthreads();
    const int l = tid & 63;
    const int h16 = (l >> 5) * 16;
    const int col = (l & 31);
#pragma unroll
    for (int g = 0; g < 2; ++g) {
      const int nfl = g * 4 + (tid >> 6);  // 0..7
      const float* src = &wlds[0][0] + nfl * 32 + col;
      i32x4 out;
#pragma unroll
      for (int q = 0; q < 4; ++q) {
        out[q] = pack4(src[(h16 + q * 4 + 0) * 256], src[(h16 + q * 4 + 1) * 256],
                       src[(h16 + q * 4 + 2) * 256], src[(h16 + q * 4 + 3) * 256],
                       1.f);
      }
      *(i32x4*)(wt_fm + (size_t)(bn * 8 + nfl) * 65536 + (size_t)kb * 1024 +
                l * 16) = out;
    }
  }
}

// ---------------------------------------------------------------------------
// prep2: x -> A_fm (i8 fragment-major) via LDS tile, fully coalesced global
// reads (L3-hot after prep1) and contiguous 8 KiB block writes.
// Block = (mf, kb): rows mf*32..+31, cols kb*256..+255. Pad 257: quant-side
// scalar LDS reads have banks (row + k + j) % 32 -> 2 lanes/bank (free).
// ---------------------------------------------------------------------------
__global__ void prep2_kernel(const float* __restrict__ x,
                             const float* __restrict__ scales_inv,
                             signed char* __restrict__ a_fm) {
  __shared__ float t[32][257];
  const int tid = threadIdx.x;
  const int mf = blockIdx.x >> 3;  // 0..255
  const int kb = blockIdx.x & 7;   // 0..7
  // Load 32x256 f32 tile, coalesced float4.
  const int c4 = tid & 63;
#pragma unroll
  for (int rr = 0; rr < 8; ++rr) {
    const int row = rr * 4 + (tid >> 6);
    const float4 v = *(const float4*)(x + (size_t)(mf * 32 + row) * K_DIM +
                                      kb * 256 + c4 * 4);
    t[row][c4 * 4 + 0] = v.x;
    t[row][c4 * 4 + 1] = v.y;
    t[row][c4 * 4 + 2] = v.z;
    t[row][c4 * 4 + 3] = v.w;
  }
  __syncthreads();
  // Quantize + pack: 2 fragment-chunks (16 B) per thread.
#pragma unroll
  for (int g = 0; g < 2; ++g) {
    const int c = g * 256 + tid;      // 0..511
    const int l = c & 63;
    const int ktl = c >> 6;           // 0..7
    const int row = l & 31;
    const int k0 = ktl * 32 + (l >> 5) * 16;
    const float si = scales_inv[mf * 32 + row];
    i32x4 out;
#pragma unroll
    for (int q = 0; q < 4; ++q) {
      out[q] = pack4(t[row][k0 + q * 4 + 0], t[row][k0 + q * 4 + 1],
                     t[row][k0 + q * 4 + 2], t[row][k0 + q * 4 + 3], si);
    }
    *(i32x4*)(a_fm + ((size_t)(mf * 64 + kb * 8 + ktl) * 64 + l) * 16) = out;
  }
}

// ---------------------------------------------------------------------------
// GEMM i8: C[M,N] f32 = (A_q i8) x (W_q i8)^T * scale_row.  UNCHANGED vs R10.
// 512 blocks (2/CU), 256 threads (4 waves 2x2), LDS 48 KiB dbuf.
// ---------------------------------------------------------------------------
__device__ __forceinline__ void async_copy16(signed char* lds_dst,
                                             const signed char* g_src) {
  __builtin_amdgcn_global_load_lds(
      (__attribute__((address_space(1))) void*)g_src,
      (__attribute__((address_space(3))) void*)lds_dst,
      16, 0, 0);
}

#define BARR() __builtin_amdgcn_s_barrier()
#define LGKM0()                                       \
  asm volatile("s_waitcnt lgkmcnt(0)" ::: "memory");  \
  __builtin_amdgcn_sched_barrier(0)
#define PRIO(p) __builtin_amdgcn_s_setprio(p)
#define VMCNT(n) asm volatile("s_waitcnt vmcnt(" #n ")" ::: "memory")

// Stage K-tile t (A 8 KiB + B 16 KiB) into buf t&1: 6 x gl_lds(16B)/thread.
#define STG6(t)                                                              \
  do {                                                                       \
    signed char* _bA = smem + ((t) & 1) * 24576;                             \
    signed char* _bB = _bA + 8192;                                           \
    const size_t _k0 = (size_t)(2 * (t)) * 1024;                             \
    async_copy16(_bA + wv * 1024 + l16,                                      \
                 Afm + (size_t)(bm4 + wv) * 65536 + _k0 + l16);              \
    async_copy16(_bA + 4096 + wv * 1024 + l16,                               \
                 Afm + (size_t)(bm4 + wv) * 65536 + _k0 + 1024 + l16);       \
    async_copy16(_bB + wv * 1024 + l16,                                      \
                 Bfm + (size_t)(bn8 + wv) * 65536 + _k0 + l16);              \
    async_copy16(_bB + 4096 + wv * 1024 + l16,                               \
                 Bfm + (size_t)(bn8 + 4 + wv) * 65536 + _k0 + l16);          \
    async_copy16(_bB + 8192 + wv * 1024 + l16,                               \
                 Bfm + (size_t)(bn8 + wv) * 65536 + _k0 + 1024 + l16);       \
    async_copy16(_bB + 12288 + wv * 1024 + l16,                              \
                 Bfm + (size_t)(bn8 + 4 + wv) * 65536 + _k0 + 1024 + l16);   \
  } while (0)

// Read the wave's 12 fragments (lane-linear, conflict-free).
#define RDT(buf)                                                             \
  do {                                                                       \
    const signed char* _bA = smem + (buf) * 24576;                           \
    const signed char* _bB = _bA + 8192;                                     \
    _Pragma("unroll") for (int nfi = 0; nfi < 4; ++nfi)                      \
      _Pragma("unroll") for (int kt = 0; kt < 2; ++kt)                       \
        bfr[nfi][kt] = *(const i32x4*)(_bB + kt * 8192 +                     \
                                       (wn4 + nfi) * 1024 + l16);            \
    _Pragma("unroll") for (int mfi = 0; mfi < 2; ++mfi)                      \
      _Pragma("unroll") for (int kt = 0; kt < 2; ++kt)                       \
        afr[mfi][kt] = *(const i32x4*)(_bA + kt * 4096 +                     \
                                       (wm2 + mfi) * 1024 + l16);            \
  } while (0)

#define MMT()                                                                \
  do {                                                                       \
    _Pragma("unroll") for (int mfi = 0; mfi < 2; ++mfi)                      \
      _Pragma("unroll") for (int nfi = 0; nfi < 4; ++nfi)                    \
        _Pragma("unroll") for (int kt = 0; kt < 2; ++kt)                     \
          acc[mfi][nfi] = __builtin_amdgcn_mfma_i32_32x32x32_i8(             \
              afr[mfi][kt], bfr[nfi][kt], acc[mfi][nfi], 0, 0, 0);           \
  } while (0)

__global__ __launch_bounds__(256, 2) void gemm_kernel(
    const signed char* __restrict__ Afm,  // i8 fragment-major [256][64][1024B]
    const signed char* __restrict__ Bfm,  // i8 fragment-major [64][64][1024B]
    const float* __restrict__ scales,     // [M] rowabsmax/127
    float* __restrict__ C) {              // f32 [M,N]
  __shared__ signed char smem[2 * 24576];  // 48 KiB
  __shared__ float scale_lds[128];

  const int tid = threadIdx.x;
  const int l = tid & 63;
  const int l16 = l * 16;
  const int wv = tid >> 6;   // 0..3
  const int wm2 = (wv >> 1) * 2;  // A frag base (mf units)
  const int wn4 = (wv & 1) * 4;   // B frag base (nf units)

  // XCD-aware swizzle: nwg=512, 64 per XCD.
  const int bid = blockIdx.x;
  const int wgid = (bid & 7) * 64 + (bid >> 3);
  const int bm = wgid >> 3;   // 0..63
  const int bn = wgid & 7;    // 0..7
  const int bm4 = bm * 4;     // A m_frag base
  const int bn8 = bn * 8;     // B n_frag base
  const int m0 = bm * 128;
  const int n0 = bn * 256;

  if (tid < 128) scale_lds[tid] = scales[m0 + tid];

  i32x16 acc[2][4] = {};
  i32x4 afr[2][2], bfr[4][2];

  STG6(0);
  STG6(1);
  VMCNT(6);  // tile0 arrived (tile1's 6 in flight)
  BARR();

#pragma unroll 1
  for (int j = 0; j < 15; ++j) {
    const int e = 2 * j;
    // tile e (buf0)
    RDT(0);
    LGKM0();
    PRIO(1); MMT(); PRIO(0);
    BARR();           // WAR: buf0 consumed
    STG6(e + 2);
    VMCNT(6);         // drain tile e+1's loads (e+2's 6 remain)
    BARR();           // publish tile e+1
    // tile e+1 (buf1)
    RDT(1);
    LGKM0();
    PRIO(1); MMT(); PRIO(0);
    BARR();           // WAR: buf1 consumed
    STG6(e + 3);
    VMCNT(6);         // drain tile e+2's loads
    BARR();           // publish tile e+2
  }
  // tile 30 (buf0): no restage; publish tile 31.
  RDT(0);
  LGKM0();
  PRIO(1); MMT(); PRIO(0);
  BARR();
  VMCNT(0);
  BARR();
  // tile 31 (buf1): final.
  RDT(1);
  LGKM0();
  PRIO(1); MMT(); PRIO(0);

  // Epilogue: C/D 32x32 layout col=lane&31, row=(reg&3)+8*(reg>>2)+4*(lane>>5).
  const int colb = n0 + (wv & 1) * 128 + (l & 31);
  const int rowb = (wv >> 1) * 64 + 4 * (l >> 5);
#pragma unroll
  for (int mfi = 0; mfi < 2; ++mfi) {
#pragma unroll
    for (int nfi = 0; nfi < 4; ++nfi) {
      const int col = colb + nfi * 32;
#pragma unroll
      for (int r = 0; r < 16; ++r) {
        const int lrow = rowb + mfi * 32 + (r & 3) + 8 * (r >> 2);
        C[(size_t)(m0 + lrow) * N_DIM + col] =
            (float)acc[mfi][nfi][r] * scale_lds[lrow];
      }
    }
  }
}

// ---------------------------------------------------------------------------
extern "C" void kernel_launch(void* const* d_in, const int* in_sizes, int n_in,
                              void* d_out, int out_size, void* d_ws,
                              size_t ws_size, hipStream_t stream) {
  const float* x = (const float*)d_in[0];  // [M,K] f32
  const float* w = (const float*)d_in[1];  // [K,N] f32
  float* out = (float*)d_out;              // [M,N] f32

  signed char* a_fm = (signed char*)d_ws + AFM_OFF;
  signed char* wt_fm = (signed char*)d_ws + WFM_OFF;
  float* scales = (float*)((char*)d_ws + SCL_OFF);
  float* scales_inv = (float*)((char*)d_ws + SCLI_OFF);

  prep1_kernel<<<2560, 256, 0, stream>>>(x, scales, scales_inv, w, wt_fm);
  prep2_kernel<<<2048, 256, 0, stream>>>(x, scales_inv, a_fm);
  gemm_kernel<<<512, 256, 0, stream>>>(a_fm, wt_fm, scales, out);
}